// Round 2
// baseline (549.733 us; speedup 1.0000x reference)
//
#include <hip/hip_runtime.h>

#define B_   8
#define N_   2048
#define C_   128
#define TI   16
#define EPS_ 0.1f

// ---------------- kernel 1: h = x @ W, alpha_l/r = h . w_att ----------------
__global__ __launch_bounds__(128) void k_h(
    const float* __restrict__ x,
    const float* __restrict__ W,
    const float* __restrict__ wl,
    const float* __restrict__ wr,
    float* __restrict__ h,
    float* __restrict__ al,
    float* __restrict__ ar)
{
    const int row = blockIdx.x;          // 0 .. B*N-1
    const int o   = threadIdx.x;         // 0 .. 127

    __shared__ float xs[C_];
    xs[o] = x[(size_t)row * C_ + o];
    __syncthreads();

    float acc = 0.f;
    #pragma unroll
    for (int i = 0; i < C_; ++i)
        acc = fmaf(xs[i], W[i * C_ + o], acc);

    h[(size_t)row * C_ + o] = acc;

    float pl = acc * wl[o];
    float pr = acc * wr[o];
    #pragma unroll
    for (int off = 32; off > 0; off >>= 1) {
        pl += __shfl_down(pl, off, 64);
        pr += __shfl_down(pr, off, 64);
    }
    __shared__ float red[4];
    if ((o & 63) == 0) { red[o >> 6] = pl; red[2 + (o >> 6)] = pr; }
    __syncthreads();
    if (o == 0) {
        al[row] = red[0] + red[1];
        ar[row] = red[2] + red[3];
    }
}

// ---- kernel 2: out[b,i,o] = sum_j mask*tanh(ar_i*al_j) * h[b,j,o] + eps*x0 ----
__global__ __launch_bounds__(128) void k_out(
    const int* __restrict__ adj,
    const float* __restrict__ h,
    const float* __restrict__ al,
    const float* __restrict__ ar,
    const float* __restrict__ x0,
    float* __restrict__ out)
{
    const int b  = blockIdx.x >> 7;            // 128 blocks per batch (N/TI)
    const int i0 = (blockIdx.x & 127) * TI;
    const int t  = threadIdx.x;                // o = t

    // alpha tile stored as 4 groups of float4: a_s4[q*128 + j] = alpha[i0+4q..4q+3][j0+j]
    __shared__ float4 a_s4[4 * 128];

    float arv[TI];
    #pragma unroll
    for (int ii = 0; ii < TI; ++ii) arv[ii] = ar[b * N_ + i0 + ii];

    float acc[TI];
    #pragma unroll
    for (int ii = 0; ii < TI; ++ii) acc[ii] = 0.f;

    const size_t hb   = (size_t)b * N_ * C_;
    const int*   adjp = adj + ((size_t)b * N_ + i0) * N_;

    for (int j0 = 0; j0 < N_; j0 += 128) {
        float alj = al[b * N_ + j0 + t];
        #pragma unroll
        for (int q = 0; q < 4; ++q) {
            float4 f;
            float* fp = (float*)&f;
            #pragma unroll
            for (int u = 0; u < 4; ++u) {
                const int ii = q * 4 + u;
                const int m  = adjp[(size_t)ii * N_ + j0 + t];
                const float z = arv[ii] * alj;
                const float e = __expf(2.f * z);       // safe: inf -> th=1, 0 -> th=-1
                const float th = 1.f - 2.f / (e + 1.f);
                fp[u] = m ? th : 0.f;
            }
            a_s4[q * 128 + t] = f;
        }
        __syncthreads();

        const float* hp = h + hb + (size_t)j0 * C_ + t;
        #pragma unroll 2
        for (int j = 0; j < 128; ++j) {
            const float hv = hp[(size_t)j * C_];
            #pragma unroll
            for (int q = 0; q < 4; ++q) {
                const float4 a4 = a_s4[q * 128 + j];   // wave-uniform broadcast
                acc[q*4+0] = fmaf(a4.x, hv, acc[q*4+0]);
                acc[q*4+1] = fmaf(a4.y, hv, acc[q*4+1]);
                acc[q*4+2] = fmaf(a4.z, hv, acc[q*4+2]);
                acc[q*4+3] = fmaf(a4.w, hv, acc[q*4+3]);
            }
        }
        __syncthreads();
    }

    #pragma unroll
    for (int ii = 0; ii < TI; ++ii) {
        const size_t oi = hb + (size_t)(i0 + ii) * C_ + t;
        out[oi] = acc[ii] + EPS_ * x0[oi];
    }
}

extern "C" void kernel_launch(void* const* d_in, const int* in_sizes, int n_in,
                              void* d_out, int out_size, void* d_ws, size_t ws_size,
                              hipStream_t stream) {
    const float* x   = (const float*)d_in[0];
    const float* x0  = (const float*)d_in[1];
    const int*   adj = (const int*)d_in[2];
    const float* W   = (const float*)d_in[3];
    const float* wl  = (const float*)d_in[4];
    const float* wr  = (const float*)d_in[5];
    float* out = (float*)d_out;

    float* h  = (float*)d_ws;                                   // 8 MB
    float* al = (float*)((char*)d_ws + (size_t)B_ * N_ * C_ * 4);
    float* ar = al + B_ * N_;

    k_h  <<<B_ * N_,        128, 0, stream>>>(x, W, wl, wr, h, al, ar);
    k_out<<<B_ * (N_ / TI), 128, 0, stream>>>(adj, h, al, ar, x0, out);
}

// Round 3
// 404.546 us; speedup vs baseline: 1.3589x; 1.3589x over previous
//
#include <hip/hip_runtime.h>
#include <stdint.h>

#define B_   8
#define N_   2048
#define C_   128
#define EPS_ 0.1f

typedef __attribute__((ext_vector_type(8))) short short8;
typedef __attribute__((ext_vector_type(4))) float f32x4;

__device__ __forceinline__ unsigned short f2bf(float f) {
    union { float f; uint32_t u; } v; v.f = f;
    uint32_t u = v.u + 0x7FFF + ((v.u >> 16) & 1);   // RNE (inputs are finite)
    return (unsigned short)(u >> 16);
}

// ---------------- kernel 0: Wt[o][k] = bf16(W[k][o]) ----------------
__global__ __launch_bounds__(128) void k_wt(const float* __restrict__ W,
                                            unsigned short* __restrict__ Wt) {
    const int o = blockIdx.x, k = threadIdx.x;
    Wt[o * C_ + k] = f2bf(W[k * C_ + o]);
}

// ---- kernel 1: ht[b][o][j]=bf16(h), al/ar = h . w_att (MFMA x@W) ----
__global__ __launch_bounds__(256) void k_h(
    const float* __restrict__ x, const unsigned short* __restrict__ Wt,
    const float* __restrict__ wl, const float* __restrict__ wr,
    unsigned short* __restrict__ ht, float* __restrict__ al, float* __restrict__ ar)
{
    const int b    = blockIdx.x >> 5;
    const int i0   = (blockIdx.x & 31) * 64;
    const int t    = threadIdx.x;
    const int lane = t & 63;
    const int wid  = t >> 6;

    // [row][k] bf16, 16 rows-of-256B, XOR-swizzled in 16B units: u' = u ^ (row&15)
    __shared__ __align__(16) unsigned short xs[64 * 128];
    __shared__ __align__(16) unsigned short ws[128 * 128];

    // stage x (fp32 -> bf16): 1024 slots of 8 elems
    #pragma unroll
    for (int p = 0; p < 4; ++p) {
        const int s = p * 256 + t, row = s >> 4, u = s & 15;
        const float* gp = x + ((size_t)(b * N_ + i0 + row) * C_ + u * 8);
        float4 f0 = *(const float4*)gp;
        float4 f1 = *(const float4*)(gp + 4);
        unsigned short tmp[8] = { f2bf(f0.x), f2bf(f0.y), f2bf(f0.z), f2bf(f0.w),
                                  f2bf(f1.x), f2bf(f1.y), f2bf(f1.z), f2bf(f1.w) };
        *(short8*)&xs[row * 128 + (u ^ (row & 15)) * 8] = *(short8*)tmp;
    }
    // stage Wt (already bf16): 2048 slots
    #pragma unroll
    for (int p = 0; p < 8; ++p) {
        const int s = p * 256 + t, o = s >> 4, u = s & 15;
        int4 v = *(const int4*)(Wt + o * C_ + u * 8);
        *(int4*)&ws[o * 128 + (u ^ (o & 15)) * 8] = v;
    }
    __syncthreads();

    const int m0 = wid * 16, lr = lane & 15, q = lane >> 4;
    f32x4 acc[8];
    #pragma unroll
    for (int i = 0; i < 8; ++i) acc[i] = (f32x4){0.f, 0.f, 0.f, 0.f};

    #pragma unroll
    for (int s = 0; s < 4; ++s) {
        const int m = m0 + lr;
        short8 af = *(const short8*)&xs[m * 128 + ((s * 4 + q) ^ (m & 15)) * 8];
        #pragma unroll
        for (int tt = 0; tt < 8; ++tt) {
            const int o = tt * 16 + lr;
            short8 bf = *(const short8*)&ws[o * 128 + ((s * 4 + q) ^ (o & 15)) * 8];
            acc[tt] = __builtin_amdgcn_mfma_f32_16x16x32_bf16(af, bf, acc[tt], 0, 0, 0);
        }
    }

    // epilogue: ht (transposed bf16) + al/ar partials
    float pl[4] = {0.f, 0.f, 0.f, 0.f}, pr[4] = {0.f, 0.f, 0.f, 0.f};
    const int j0 = i0 + m0 + q * 4;     // D rows = j index, 4 consecutive
    #pragma unroll
    for (int tt = 0; tt < 8; ++tt) {
        const int o = tt * 16 + lr;
        const float wlv = wl[o], wrv = wr[o];
        unsigned int lo = (unsigned int)f2bf(acc[tt][0]) | ((unsigned int)f2bf(acc[tt][1]) << 16);
        unsigned int hi = (unsigned int)f2bf(acc[tt][2]) | ((unsigned int)f2bf(acc[tt][3]) << 16);
        uint2 u2; u2.x = lo; u2.y = hi;
        *(uint2*)&ht[((size_t)(b * C_ + o)) * N_ + j0] = u2;
        #pragma unroll
        for (int r = 0; r < 4; ++r) {
            pl[r] = fmaf(acc[tt][r], wlv, pl[r]);
            pr[r] = fmaf(acc[tt][r], wrv, pr[r]);
        }
    }
    #pragma unroll
    for (int msk = 1; msk < 16; msk <<= 1) {
        #pragma unroll
        for (int r = 0; r < 4; ++r) {
            pl[r] += __shfl_xor(pl[r], msk, 64);
            pr[r] += __shfl_xor(pr[r], msk, 64);
        }
    }
    if (lr == 0) {
        #pragma unroll
        for (int r = 0; r < 4; ++r) {
            al[b * N_ + j0 + r] = pl[r];
            ar[b * N_ + j0 + r] = pr[r];
        }
    }
}

// ---- kernel 2: out = mask(tanh(ar_i*al_j)) @ h + eps*x0  (MFMA) ----
__global__ __launch_bounds__(512) void k_out(
    const int* __restrict__ adj, const unsigned short* __restrict__ ht,
    const float* __restrict__ al, const float* __restrict__ ar,
    const float* __restrict__ x0, float* __restrict__ out)
{
    const int b    = blockIdx.x >> 5;
    const int i0   = (blockIdx.x & 31) * 64;
    const int t    = threadIdx.x;
    const int lane = t & 63;
    const int wid  = t >> 6;

    // K-chunk = 64 j. XOR-swizzled 16B units: u' = u ^ (row&7)
    __shared__ __align__(16) unsigned short a_s[64 * 64];    // alpha [m][j]  8 KB
    __shared__ __align__(16) unsigned short h_s[128 * 64];   // ht    [o][j] 16 KB

    const int arow = t >> 3;            // 0..63 (i-row within tile)
    const int jq   = t & 7;             // 8-j unit within chunk
    const float arv = ar[b * N_ + i0 + arow];
    const int ho1 = t >> 3;             // ht staging rows: ho1 and ho1+64

    int4   adjA[2], adjB[2];
    int4   htA[2], htB[2];
    float4 alA[2], alB[2];

    auto ldc = [&](int c, int p) {
        const int j0 = c * 64;
        const int* ap = adj + ((size_t)(b * N_) + i0 + arow) * N_ + j0 + jq * 8;
        adjA[p] = *(const int4*)ap;
        adjB[p] = *(const int4*)(ap + 4);
        const unsigned short* hp = ht + (size_t)b * C_ * N_ + j0 + jq * 8;
        htA[p] = *(const int4*)(hp + (size_t)ho1 * N_);
        htB[p] = *(const int4*)(hp + (size_t)(ho1 + 64) * N_);
        const float* alp = al + b * N_ + j0 + jq * 8;
        alA[p] = *(const float4*)alp;
        alB[p] = *(const float4*)(alp + 4);
    };

    ldc(0, 0);
    ldc(1, 1);

    const int m0 = (wid & 3) * 16, n0 = (wid >> 2) * 64;
    const int lr = lane & 15, q = lane >> 4;
    f32x4 acc[4];
    #pragma unroll
    for (int i = 0; i < 4; ++i) acc[i] = (f32x4){0.f, 0.f, 0.f, 0.f};

    for (int c = 0; c < 32; ++c) {
        const int p = c & 1;
        __syncthreads();                               // prev MFMA reads done

        // ---- alpha tile -> LDS ----
        const int*   av = (const int*)&adjA[p];        // adjA/adjB adjacent in layout below
        const int*   bv = (const int*)&adjB[p];
        const float* af = (const float*)&alA[p];
        const float* bf = (const float*)&alB[p];
        unsigned short packed[8];
        #pragma unroll
        for (int e = 0; e < 4; ++e) {
            float z  = arv * af[e];
            float ex = __expf(2.f * z);
            float th = 1.f - 2.f / (ex + 1.f);
            packed[e] = av[e] ? f2bf(th) : (unsigned short)0;
        }
        #pragma unroll
        for (int e = 0; e < 4; ++e) {
            float z  = arv * bf[e];
            float ex = __expf(2.f * z);
            float th = 1.f - 2.f / (ex + 1.f);
            packed[4 + e] = bv[e] ? f2bf(th) : (unsigned short)0;
        }
        *(short8*)&a_s[arow * 64 + (jq ^ (arow & 7)) * 8] = *(short8*)packed;

        // ---- ht tiles -> LDS ----
        *(int4*)&h_s[ho1 * 64 + (jq ^ (ho1 & 7)) * 8]        = htA[p];
        *(int4*)&h_s[(ho1 + 64) * 64 + (jq ^ (ho1 & 7)) * 8] = htB[p];

        if (c + 2 < 32) ldc(c + 2, p);                 // prefetch depth 2
        __syncthreads();

        // ---- MFMA phase ----
        #pragma unroll
        for (int s2 = 0; s2 < 2; ++s2) {
            const int m = m0 + lr;
            short8 afr = *(const short8*)&a_s[m * 64 + ((s2 * 4 + q) ^ (m & 7)) * 8];
            #pragma unroll
            for (int tt = 0; tt < 4; ++tt) {
                const int o = n0 + tt * 16 + lr;
                short8 bfr = *(const short8*)&h_s[o * 64 + ((s2 * 4 + q) ^ (o & 7)) * 8];
                acc[tt] = __builtin_amdgcn_mfma_f32_16x16x32_bf16(afr, bfr, acc[tt], 0, 0, 0);
            }
        }
    }

    // ---- epilogue: out = acc + eps*x0 ----
    #pragma unroll
    for (int tt = 0; tt < 4; ++tt) {
        const int o = n0 + tt * 16 + lr;
        #pragma unroll
        for (int r = 0; r < 4; ++r) {
            const int row = i0 + m0 + q * 4 + r;
            const size_t idx = ((size_t)(b * N_) + row) * C_ + o;
            out[idx] = acc[tt][r] + EPS_ * x0[idx];
        }
    }
}

extern "C" void kernel_launch(void* const* d_in, const int* in_sizes, int n_in,
                              void* d_out, int out_size, void* d_ws, size_t ws_size,
                              hipStream_t stream) {
    const float* x   = (const float*)d_in[0];
    const float* x0  = (const float*)d_in[1];
    const int*   adj = (const int*)d_in[2];
    const float* W   = (const float*)d_in[3];
    const float* wl  = (const float*)d_in[4];
    const float* wr  = (const float*)d_in[5];
    float* out = (float*)d_out;

    unsigned short* ht = (unsigned short*)d_ws;                      // 4 MB
    float* al = (float*)((char*)d_ws + (size_t)B_ * C_ * N_ * 2);
    float* ar = al + B_ * N_;
    unsigned short* Wt = (unsigned short*)(ar + B_ * N_);            // 32 KB

    k_wt <<<C_,            C_,  0, stream>>>(W, Wt);
    k_h  <<<B_ * (N_ / 64), 256, 0, stream>>>(x, Wt, wl, wr, ht, al, ar);
    k_out<<<B_ * (N_ / 64), 512, 0, stream>>>(adj, ht, al, ar, x0, out);
}

// Round 4
// 235.067 us; speedup vs baseline: 2.3386x; 1.7210x over previous
//
#include <hip/hip_runtime.h>
#include <stdint.h>

#define B_   8
#define N_   2048
#define C_   128
#define EPS_ 0.1f

typedef __attribute__((ext_vector_type(8))) short short8;
typedef __attribute__((ext_vector_type(4))) float f32x4;

__device__ __forceinline__ unsigned short f2bf(float f) {
    union { float f; uint32_t u; } v; v.f = f;
    uint32_t u = v.u + 0x7FFF + ((v.u >> 16) & 1);   // RNE (inputs are finite)
    return (unsigned short)(u >> 16);
}

// ---------------- kernel 0: Wt[o][k] = bf16(W[k][o]) ----------------
__global__ __launch_bounds__(128) void k_wt(const float* __restrict__ W,
                                            unsigned short* __restrict__ Wt) {
    const int o = blockIdx.x, k = threadIdx.x;
    Wt[o * C_ + k] = f2bf(W[k * C_ + o]);
}

// ---- kernel 1: ht[b][o][j]=bf16(h), al/ar = h . w_att (MFMA x@W) ----
__global__ __launch_bounds__(256) void k_h(
    const float* __restrict__ x, const unsigned short* __restrict__ Wt,
    const float* __restrict__ wl, const float* __restrict__ wr,
    unsigned short* __restrict__ ht, float* __restrict__ al, float* __restrict__ ar)
{
    const int b    = blockIdx.x >> 5;
    const int i0   = (blockIdx.x & 31) * 64;
    const int t    = threadIdx.x;
    const int lane = t & 63;
    const int wid  = t >> 6;

    // [row][k] bf16, XOR-swizzled in 16B units: u' = u ^ (row&15)
    __shared__ __align__(16) unsigned short xs[64 * 128];
    __shared__ __align__(16) unsigned short ws[128 * 128];

    // stage x (fp32 -> bf16)
    #pragma unroll
    for (int p = 0; p < 4; ++p) {
        const int s = p * 256 + t, row = s >> 4, u = s & 15;
        const float* gp = x + ((size_t)(b * N_ + i0 + row) * C_ + u * 8);
        float4 f0 = *(const float4*)gp;
        float4 f1 = *(const float4*)(gp + 4);
        short8 tv;
        tv[0] = (short)f2bf(f0.x); tv[1] = (short)f2bf(f0.y);
        tv[2] = (short)f2bf(f0.z); tv[3] = (short)f2bf(f0.w);
        tv[4] = (short)f2bf(f1.x); tv[5] = (short)f2bf(f1.y);
        tv[6] = (short)f2bf(f1.z); tv[7] = (short)f2bf(f1.w);
        *(short8*)&xs[row * 128 + (u ^ (row & 15)) * 8] = tv;
    }
    // stage Wt (already bf16)
    #pragma unroll
    for (int p = 0; p < 8; ++p) {
        const int s = p * 256 + t, o = s >> 4, u = s & 15;
        int4 v = *(const int4*)(Wt + o * C_ + u * 8);
        *(int4*)&ws[o * 128 + (u ^ (o & 15)) * 8] = v;
    }
    __syncthreads();

    const int m0 = wid * 16, lr = lane & 15, q = lane >> 4;
    f32x4 acc[8];
    #pragma unroll
    for (int i = 0; i < 8; ++i) acc[i] = (f32x4){0.f, 0.f, 0.f, 0.f};

    #pragma unroll
    for (int s = 0; s < 4; ++s) {
        const int m = m0 + lr;
        short8 af = *(const short8*)&xs[m * 128 + ((s * 4 + q) ^ (m & 15)) * 8];
        #pragma unroll
        for (int tt = 0; tt < 8; ++tt) {
            const int o = tt * 16 + lr;
            short8 bf = *(const short8*)&ws[o * 128 + ((s * 4 + q) ^ (o & 15)) * 8];
            acc[tt] = __builtin_amdgcn_mfma_f32_16x16x32_bf16(af, bf, acc[tt], 0, 0, 0);
        }
    }

    // epilogue: ht (transposed bf16) + al/ar partials
    float pl[4] = {0.f, 0.f, 0.f, 0.f}, pr[4] = {0.f, 0.f, 0.f, 0.f};
    const int j0 = i0 + m0 + q * 4;     // D rows = j index, 4 consecutive
    #pragma unroll
    for (int tt = 0; tt < 8; ++tt) {
        const int o = tt * 16 + lr;
        const float wlv = wl[o], wrv = wr[o];
        unsigned int lo = (unsigned int)f2bf(acc[tt][0]) | ((unsigned int)f2bf(acc[tt][1]) << 16);
        unsigned int hi = (unsigned int)f2bf(acc[tt][2]) | ((unsigned int)f2bf(acc[tt][3]) << 16);
        uint2 u2; u2.x = lo; u2.y = hi;
        *(uint2*)&ht[((size_t)(b * C_ + o)) * N_ + j0] = u2;
        #pragma unroll
        for (int r = 0; r < 4; ++r) {
            pl[r] = fmaf(acc[tt][r], wlv, pl[r]);
            pr[r] = fmaf(acc[tt][r], wrv, pr[r]);
        }
    }
    #pragma unroll
    for (int msk = 1; msk < 16; msk <<= 1) {
        #pragma unroll
        for (int r = 0; r < 4; ++r) {
            pl[r] += __shfl_xor(pl[r], msk, 64);
            pr[r] += __shfl_xor(pr[r], msk, 64);
        }
    }
    if (lr == 0) {
        #pragma unroll
        for (int r = 0; r < 4; ++r) {
            al[b * N_ + j0 + r] = pl[r];
            ar[b * N_ + j0 + r] = pr[r];
        }
    }
}

// ---- kernel 2: out = mask(tanh(ar_i*al_j)) @ h + eps*x0  (MFMA) ----
struct Pref {                       // one K-chunk of prefetched operands
    int4   a0, a1;                  // adj, 8 ints (j = jq*8 + 0..7)
    int4   h0, h1;                  // ht rows ho1, ho1+64 (8 bf16 each)
    float4 l0, l1;                  // al, 8 floats
};

__global__ __launch_bounds__(512) void k_out(
    const int* __restrict__ adj, const unsigned short* __restrict__ ht,
    const float* __restrict__ al, const float* __restrict__ ar,
    const float* __restrict__ x0, float* __restrict__ out)
{
    const int b    = blockIdx.x >> 5;
    const int i0   = (blockIdx.x & 31) * 64;
    const int t    = threadIdx.x;
    const int lane = t & 63;
    const int wid  = t >> 6;

    // K-chunk = 64 j. XOR-swizzled 16B units: u' = u ^ (row&7)
    __shared__ __align__(16) unsigned short a_s[64 * 64];    // alpha [m][j]  8 KB
    __shared__ __align__(16) unsigned short h_s[128 * 64];   // ht    [o][j] 16 KB

    const int arow = t >> 3;            // 0..63 (i-row within tile)
    const int jq   = t & 7;             // 8-j unit within chunk
    const float arv = ar[b * N_ + i0 + arow];
    const int ho1 = t >> 3;             // ht staging rows: ho1 and ho1+64

    auto ldc = [&](int c) -> Pref {
        Pref P;
        const int j0 = c * 64;
        const int* ap = adj + ((size_t)(b * N_) + i0 + arow) * N_ + j0 + jq * 8;
        P.a0 = *(const int4*)ap;
        P.a1 = *(const int4*)(ap + 4);
        const unsigned short* hp = ht + (size_t)b * C_ * N_ + j0 + jq * 8;
        P.h0 = *(const int4*)(hp + (size_t)ho1 * N_);
        P.h1 = *(const int4*)(hp + (size_t)(ho1 + 64) * N_);
        const float* alp = al + b * N_ + j0 + jq * 8;
        P.l0 = *(const float4*)alp;
        P.l1 = *(const float4*)(alp + 4);
        return P;
    };

    auto stage = [&](const Pref& P) {
        short8 pk;
        const int*   av = (const int*)&P.a0;
        const int*   bv = (const int*)&P.a1;
        const float* af = (const float*)&P.l0;
        const float* bf = (const float*)&P.l1;
        #pragma unroll
        for (int e = 0; e < 4; ++e) {
            float z  = arv * af[e];
            float ex = __expf(2.f * z);
            float th = 1.f - 2.f / (ex + 1.f);
            pk[e] = av[e] ? (short)f2bf(th) : (short)0;
        }
        #pragma unroll
        for (int e = 0; e < 4; ++e) {
            float z  = arv * bf[e];
            float ex = __expf(2.f * z);
            float th = 1.f - 2.f / (ex + 1.f);
            pk[4 + e] = bv[e] ? (short)f2bf(th) : (short)0;
        }
        *(short8*)&a_s[arow * 64 + (jq ^ (arow & 7)) * 8] = pk;
        *(int4*)&h_s[ho1 * 64 + (jq ^ (ho1 & 7)) * 8]        = P.h0;
        *(int4*)&h_s[(ho1 + 64) * 64 + (jq ^ (ho1 & 7)) * 8] = P.h1;
    };

    const int m0 = (wid & 3) * 16, n0 = (wid >> 2) * 64;
    const int lr = lane & 15, q = lane >> 4;
    f32x4 acc[4];
    #pragma unroll
    for (int i = 0; i < 4; ++i) acc[i] = (f32x4){0.f, 0.f, 0.f, 0.f};

    auto mma = [&]() {
        #pragma unroll
        for (int s2 = 0; s2 < 2; ++s2) {
            const int m = m0 + lr;
            short8 afr = *(const short8*)&a_s[m * 64 + ((s2 * 4 + q) ^ (m & 7)) * 8];
            #pragma unroll
            for (int tt = 0; tt < 4; ++tt) {
                const int o = n0 + tt * 16 + lr;
                short8 bfr = *(const short8*)&h_s[o * 64 + ((s2 * 4 + q) ^ (o & 7)) * 8];
                acc[tt] = __builtin_amdgcn_mfma_f32_16x16x32_bf16(afr, bfr, acc[tt], 0, 0, 0);
            }
        }
    };

    Pref p0 = ldc(0);
    Pref p1 = ldc(1);

    for (int cc = 0; cc < 16; ++cc) {
        __syncthreads();                   // prev MFMA reads done
        stage(p0);
        if (cc < 15) p0 = ldc(2 * cc + 2); // prefetch depth 2, constant slot
        __syncthreads();
        mma();

        __syncthreads();
        stage(p1);
        if (cc < 15) p1 = ldc(2 * cc + 3);
        __syncthreads();
        mma();
    }

    // ---- epilogue: out = acc + eps*x0 ----
    #pragma unroll
    for (int tt = 0; tt < 4; ++tt) {
        const int o = n0 + tt * 16 + lr;
        #pragma unroll
        for (int r = 0; r < 4; ++r) {
            const int row = i0 + m0 + q * 4 + r;
            const size_t idx = ((size_t)(b * N_) + row) * C_ + o;
            out[idx] = acc[tt][r] + EPS_ * x0[idx];
        }
    }
}

extern "C" void kernel_launch(void* const* d_in, const int* in_sizes, int n_in,
                              void* d_out, int out_size, void* d_ws, size_t ws_size,
                              hipStream_t stream) {
    const float* x   = (const float*)d_in[0];
    const float* x0  = (const float*)d_in[1];
    const int*   adj = (const int*)d_in[2];
    const float* W   = (const float*)d_in[3];
    const float* wl  = (const float*)d_in[4];
    const float* wr  = (const float*)d_in[5];
    float* out = (float*)d_out;

    unsigned short* ht = (unsigned short*)d_ws;                      // 4 MB
    float* al = (float*)((char*)d_ws + (size_t)B_ * C_ * N_ * 2);
    float* ar = al + B_ * N_;
    unsigned short* Wt = (unsigned short*)(ar + B_ * N_);            // 32 KB

    k_wt <<<C_,             C_,  0, stream>>>(W, Wt);
    k_h  <<<B_ * (N_ / 64), 256, 0, stream>>>(x, Wt, wl, wr, ht, al, ar);
    k_out<<<B_ * (N_ / 64), 512, 0, stream>>>(adj, ht, al, ar, x0, out);
}

// Round 5
// 228.412 us; speedup vs baseline: 2.4068x; 1.0291x over previous
//
#include <hip/hip_runtime.h>
#include <stdint.h>

#define B_   8
#define N_   2048
#define C_   128
#define EPS_ 0.1f

typedef __attribute__((ext_vector_type(8))) short short8;
typedef __attribute__((ext_vector_type(4))) float f32x4;

__device__ __forceinline__ unsigned short f2bf(float f) {
    union { float f; uint32_t u; } v; v.f = f;
    uint32_t u = v.u + 0x7FFF + ((v.u >> 16) & 1);   // RNE (inputs are finite)
    return (unsigned short)(u >> 16);
}

// ---------------- kernel 0: Wt[o][k] = bf16(W[k][o]) ----------------
__global__ __launch_bounds__(128) void k_wt(const float* __restrict__ W,
                                            unsigned short* __restrict__ Wt) {
    const int o = blockIdx.x, k = threadIdx.x;
    Wt[o * C_ + k] = f2bf(W[k * C_ + o]);
}

// ---- kernel 1: ht[b][o][j]=bf16(h), al/ar = h . w_att (MFMA x@W) ----
__global__ __launch_bounds__(256) void k_h(
    const float* __restrict__ x, const unsigned short* __restrict__ Wt,
    const float* __restrict__ wl, const float* __restrict__ wr,
    unsigned short* __restrict__ ht, float* __restrict__ al, float* __restrict__ ar)
{
    const int b    = blockIdx.x >> 5;
    const int i0   = (blockIdx.x & 31) * 64;
    const int t    = threadIdx.x;
    const int lane = t & 63;
    const int wid  = t >> 6;

    // [row][k] bf16, XOR-swizzled in 16B units: u' = u ^ (row&15)
    __shared__ __align__(16) unsigned short xs[64 * 128];
    __shared__ __align__(16) unsigned short ws[128 * 128];

    // stage x (fp32 -> bf16)
    #pragma unroll
    for (int p = 0; p < 4; ++p) {
        const int s = p * 256 + t, row = s >> 4, u = s & 15;
        const float* gp = x + ((size_t)(b * N_ + i0 + row) * C_ + u * 8);
        float4 f0 = *(const float4*)gp;
        float4 f1 = *(const float4*)(gp + 4);
        short8 tv;
        tv[0] = (short)f2bf(f0.x); tv[1] = (short)f2bf(f0.y);
        tv[2] = (short)f2bf(f0.z); tv[3] = (short)f2bf(f0.w);
        tv[4] = (short)f2bf(f1.x); tv[5] = (short)f2bf(f1.y);
        tv[6] = (short)f2bf(f1.z); tv[7] = (short)f2bf(f1.w);
        *(short8*)&xs[row * 128 + (u ^ (row & 15)) * 8] = tv;
    }
    // stage Wt (already bf16)
    #pragma unroll
    for (int p = 0; p < 8; ++p) {
        const int s = p * 256 + t, o = s >> 4, u = s & 15;
        int4 v = *(const int4*)(Wt + o * C_ + u * 8);
        *(int4*)&ws[o * 128 + (u ^ (o & 15)) * 8] = v;
    }
    __syncthreads();

    const int m0 = wid * 16, lr = lane & 15, q = lane >> 4;
    f32x4 acc[8];
    #pragma unroll
    for (int i = 0; i < 8; ++i) acc[i] = (f32x4){0.f, 0.f, 0.f, 0.f};

    #pragma unroll
    for (int s = 0; s < 4; ++s) {
        const int m = m0 + lr;
        short8 af = *(const short8*)&xs[m * 128 + ((s * 4 + q) ^ (m & 15)) * 8];
        #pragma unroll
        for (int tt = 0; tt < 8; ++tt) {
            const int o = tt * 16 + lr;
            short8 bf = *(const short8*)&ws[o * 128 + ((s * 4 + q) ^ (o & 15)) * 8];
            acc[tt] = __builtin_amdgcn_mfma_f32_16x16x32_bf16(af, bf, acc[tt], 0, 0, 0);
        }
    }

    // epilogue: ht (transposed bf16) + al/ar partials
    float pl[4] = {0.f, 0.f, 0.f, 0.f}, pr[4] = {0.f, 0.f, 0.f, 0.f};
    const int j0 = i0 + m0 + q * 4;     // D rows = j index, 4 consecutive
    #pragma unroll
    for (int tt = 0; tt < 8; ++tt) {
        const int o = tt * 16 + lr;
        const float wlv = wl[o], wrv = wr[o];
        unsigned int lo = (unsigned int)f2bf(acc[tt][0]) | ((unsigned int)f2bf(acc[tt][1]) << 16);
        unsigned int hi = (unsigned int)f2bf(acc[tt][2]) | ((unsigned int)f2bf(acc[tt][3]) << 16);
        uint2 u2; u2.x = lo; u2.y = hi;
        *(uint2*)&ht[((size_t)(b * C_ + o)) * N_ + j0] = u2;
        #pragma unroll
        for (int r = 0; r < 4; ++r) {
            pl[r] = fmaf(acc[tt][r], wlv, pl[r]);
            pr[r] = fmaf(acc[tt][r], wrv, pr[r]);
        }
    }
    #pragma unroll
    for (int msk = 1; msk < 16; msk <<= 1) {
        #pragma unroll
        for (int r = 0; r < 4; ++r) {
            pl[r] += __shfl_xor(pl[r], msk, 64);
            pr[r] += __shfl_xor(pr[r], msk, 64);
        }
    }
    if (lr == 0) {
        #pragma unroll
        for (int r = 0; r < 4; ++r) {
            al[b * N_ + j0 + r] = pl[r];
            ar[b * N_ + j0 + r] = pr[r];
        }
    }
}

// ---- kernel 2: out = mask(tanh(ar_i*al_j)) @ h + eps*x0  (MFMA) ----
// 512 blocks x 256 thr; i-tile 32, C-tile 32x128; double-buffered LDS, 1 barrier/chunk.
struct Pref {                       // one K-chunk of prefetched operands
    int4   a0, a1;                  // adj, 8 ints (j = jq*8 + 0..7)
    int4   h0, h1, h2, h3;          // ht rows ho, ho+32, ho+64, ho+96
    float4 l0, l1;                  // al, 8 floats
};

__global__ __launch_bounds__(256) void k_out(
    const int* __restrict__ adj, const unsigned short* __restrict__ ht,
    const float* __restrict__ al, const float* __restrict__ ar,
    const float* __restrict__ x0, float* __restrict__ out)
{
    const int b    = blockIdx.x >> 6;
    const int i0   = (blockIdx.x & 63) * 32;
    const int t    = threadIdx.x;
    const int lane = t & 63;
    const int wid  = t >> 6;

    // K-chunk = 64 j, double-buffered. XOR-swizzled 16B units: u' = u ^ (row&7)
    __shared__ __align__(16) unsigned short a_s[2][32 * 64];    //  8 KB
    __shared__ __align__(16) unsigned short h_s[2][128 * 64];   // 32 KB

    const int arow = t >> 3;            // 0..31 (i-row within tile; also ht stage row)
    const int jq   = t & 7;             // 8-j unit within chunk
    const float arv = ar[b * N_ + i0 + arow];

    auto ldc = [&](int c) -> Pref {
        Pref P;
        const int j0 = c * 64;
        const int* ap = adj + ((size_t)(b * N_) + i0 + arow) * N_ + j0 + jq * 8;
        P.a0 = *(const int4*)ap;
        P.a1 = *(const int4*)(ap + 4);
        const unsigned short* hp = ht + (size_t)b * C_ * N_ + j0 + jq * 8;
        P.h0 = *(const int4*)(hp + (size_t)arow * N_);
        P.h1 = *(const int4*)(hp + (size_t)(arow + 32) * N_);
        P.h2 = *(const int4*)(hp + (size_t)(arow + 64) * N_);
        P.h3 = *(const int4*)(hp + (size_t)(arow + 96) * N_);
        const float* alp = al + b * N_ + j0 + jq * 8;
        P.l0 = *(const float4*)alp;
        P.l1 = *(const float4*)(alp + 4);
        return P;
    };

    auto stage = [&](int buf, const Pref& P) {
        short8 pk;
        const int*   av = (const int*)&P.a0;
        const int*   bv = (const int*)&P.a1;
        const float* af = (const float*)&P.l0;
        const float* bf = (const float*)&P.l1;
        #pragma unroll
        for (int e = 0; e < 4; ++e) {
            float z  = arv * af[e];
            float ex = __expf(2.f * z);
            float th = 1.f - 2.f / (ex + 1.f);
            pk[e] = av[e] ? (short)f2bf(th) : (short)0;
        }
        #pragma unroll
        for (int e = 0; e < 4; ++e) {
            float z  = arv * bf[e];
            float ex = __expf(2.f * z);
            float th = 1.f - 2.f / (ex + 1.f);
            pk[4 + e] = bv[e] ? (short)f2bf(th) : (short)0;
        }
        const int su = (jq ^ (arow & 7)) * 8;
        *(short8*)&a_s[buf][arow * 64 + su] = pk;
        *(int4*)&h_s[buf][(arow)      * 64 + su] = P.h0;
        *(int4*)&h_s[buf][(arow + 32) * 64 + su] = P.h1;
        *(int4*)&h_s[buf][(arow + 64) * 64 + su] = P.h2;
        *(int4*)&h_s[buf][(arow + 96) * 64 + su] = P.h3;
    };

    const int m0 = (wid & 1) * 16, n0 = (wid >> 1) * 64;
    const int lr = lane & 15, q = lane >> 4;
    f32x4 acc[4];
    #pragma unroll
    for (int i = 0; i < 4; ++i) acc[i] = (f32x4){0.f, 0.f, 0.f, 0.f};

    auto mma = [&](int buf) {
        #pragma unroll
        for (int s2 = 0; s2 < 2; ++s2) {
            const int m = m0 + lr;
            short8 afr = *(const short8*)&a_s[buf][m * 64 + ((s2 * 4 + q) ^ (m & 7)) * 8];
            #pragma unroll
            for (int tt = 0; tt < 4; ++tt) {
                const int o = n0 + tt * 16 + lr;
                short8 bfr = *(const short8*)&h_s[buf][o * 64 + ((s2 * 4 + q) ^ (o & 7)) * 8];
                acc[tt] = __builtin_amdgcn_mfma_f32_16x16x32_bf16(afr, bfr, acc[tt], 0, 0, 0);
            }
        }
    };

    // Preamble: buf0 <- chunk0; pA = chunk1, pB = chunk2.
    {
        Pref p = ldc(0);
        stage(0, p);
    }
    Pref pA = ldc(1);
    Pref pB = ldc(2);
    __syncthreads();

    // Invariant at top of iter cc: buf0 = chunk 2cc, pA = chunk 2cc+1, pB = chunk 2cc+2.
    for (int cc = 0; cc < 16; ++cc) {
        stage(1, pA);                       // buf1 <- chunk 2cc+1
        if (cc < 15) pA = ldc(2 * cc + 3);
        mma(0);                             // chunk 2cc
        __syncthreads();

        if (cc < 15) {
            stage(0, pB);                   // buf0 <- chunk 2cc+2
            if (cc < 14) pB = ldc(2 * cc + 4);
        }
        mma(1);                             // chunk 2cc+1
        __syncthreads();
    }

    // ---- epilogue: out = acc + eps*x0 ----
    #pragma unroll
    for (int tt = 0; tt < 4; ++tt) {
        const int o = n0 + tt * 16 + lr;
        #pragma unroll
        for (int r = 0; r < 4; ++r) {
            const int row = i0 + m0 + q * 4 + r;
            const size_t idx = ((size_t)(b * N_) + row) * C_ + o;
            out[idx] = acc[tt][r] + EPS_ * x0[idx];
        }
    }
}

extern "C" void kernel_launch(void* const* d_in, const int* in_sizes, int n_in,
                              void* d_out, int out_size, void* d_ws, size_t ws_size,
                              hipStream_t stream) {
    const float* x   = (const float*)d_in[0];
    const float* x0  = (const float*)d_in[1];
    const int*   adj = (const int*)d_in[2];
    const float* W   = (const float*)d_in[3];
    const float* wl  = (const float*)d_in[4];
    const float* wr  = (const float*)d_in[5];
    float* out = (float*)d_out;

    unsigned short* ht = (unsigned short*)d_ws;                      // 4 MB
    float* al = (float*)((char*)d_ws + (size_t)B_ * C_ * N_ * 2);
    float* ar = al + B_ * N_;
    unsigned short* Wt = (unsigned short*)(ar + B_ * N_);            // 32 KB

    k_wt <<<C_,             C_,  0, stream>>>(W, Wt);
    k_h  <<<B_ * (N_ / 64), 256, 0, stream>>>(x, Wt, wl, wr, ht, al, ar);
    k_out<<<B_ * (N_ / 32), 256, 0, stream>>>(adj, ht, al, ar, x0, out);
}